// Round 14
// baseline (95.681 us; speedup 1.0000x reference)
//
#include <hip/hip_runtime.h>
#include <hip/hip_bf16.h>

// out[tgt[i], :] += x[src[i], :] * e[i]   (fp32, D=32)
// Radix partition by 128-node target bucket; bf16 x table (row = one 64B
// line); per-bucket apply rank-sorts records, register-accumulated gather.
// Round 14: non-temporal hints on ALL read-once/write-once streams
// (rec, tgt/src/e, out) so the 6.4 MB bf16 x table keeps the per-XCD 4 MiB
// L2 to itself. Structure identical to round 13 (58.3 us).

#define D_FEAT   32
#define SHIFT    7            // 128 nodes per bucket
#define BNODES   128
#define CHUNK    8192         // edges per partition block
#define MAXNB    1024
#define CAP      3072         // max records stageable in LDS per bucket
#define ATHR     512          // apply block threads
#define KMAX     (CAP / ATHR) // records per thread in staging (6)

typedef int   v4i __attribute__((ext_vector_type(4)));
typedef float v4f __attribute__((ext_vector_type(4)));
typedef int   v2i __attribute__((ext_vector_type(2)));
typedef float v2f __attribute__((ext_vector_type(2)));

__device__ __forceinline__ unsigned short f2bf(float v) {
    union { float f; unsigned int u; } c; c.f = v;
    unsigned int r = c.u + 0x7FFFu + ((c.u >> 16) & 1u);   // round-nearest-even
    return (unsigned short)(r >> 16);
}

__device__ __forceinline__ v4i ldnt4i(const int* p)   { return __builtin_nontemporal_load((const v4i*)p); }
__device__ __forceinline__ v4f ldnt4f(const float* p) { return __builtin_nontemporal_load((const v4f*)p); }
__device__ __forceinline__ int2 ldnt2i(const int2* p) {
    v2i r = __builtin_nontemporal_load((const v2i*)p);
    return make_int2(r.x, r.y);
}
__device__ __forceinline__ void stnt2i(int2* p, int a, int b) {
    v2i r; r.x = a; r.y = b;
    __builtin_nontemporal_store(r, (v2i*)p);
}
__device__ __forceinline__ void stnt2f(float* p, float a, float b) {
    v2f r; r.x = a; r.y = b;
    __builtin_nontemporal_store(r, (v2f*)p);
}

// ---------------- fallback path (round-2, verified) ----------------
__global__ void zero_out_kernel(float* __restrict__ out, int n) {
    int i = blockIdx.x * blockDim.x + threadIdx.x;
    if (i < n) out[i] = 0.0f;
}

__global__ void scatter_add_kernel(const float* __restrict__ x,
                                   const int* __restrict__ src,
                                   const int* __restrict__ tgt,
                                   const float* __restrict__ e,
                                   float* __restrict__ out,
                                   int n_edges) {
    long long gid   = (long long)blockIdx.x * blockDim.x + threadIdx.x;
    long long total = (long long)n_edges * D_FEAT;
    if (gid >= total) return;
    int edge = (int)(gid >> 5);
    int f    = (int)(gid & 31);
    float m = x[(long long)src[edge] * D_FEAT + f] * e[edge];
    atomicAdd(&out[(long long)tgt[edge] * D_FEAT + f], m);
}

// ---------------- radix path ----------------

// conv (grid-stride prologue) + per-chunk histogram of target buckets.
// xh == nullptr skips the conv (f32 tier).
__global__ __launch_bounds__(1024) void p1_hist_kernel(
        const float* __restrict__ x, unsigned short* __restrict__ xh, int n_x,
        const int* __restrict__ tgt, int* __restrict__ Hg,
        int n_edges, int NB, int nchunks) {
    // ---- conv x -> bf16 (x read once -> NT; xh is the reused table) ----
    if (xh) {
        int n4 = n_x >> 2;
        for (int i = blockIdx.x * 1024 + threadIdx.x; i < n4; i += nchunks * 1024) {
            v4f v = ldnt4f(x + (i << 2));
            ushort4 h;
            h.x = f2bf(v.x); h.y = f2bf(v.y); h.z = f2bf(v.z); h.w = f2bf(v.w);
            ((ushort4*)xh)[i] = h;
        }
        if (blockIdx.x == 0) {
            for (int j = (n4 << 2) + threadIdx.x; j < n_x; j += 1024)
                xh[j] = f2bf(x[j]);
        }
    }
    // ---- histogram (tgt read -> NT) ----
    __shared__ int cnt[MAXNB];
    for (int i = threadIdx.x; i < NB; i += 1024) cnt[i] = 0;
    __syncthreads();
    int base = blockIdx.x * CHUNK;
    int lim  = min(base + CHUNK, n_edges);
    int n    = lim - base;
    int nv   = n >> 2;
    for (int v = threadIdx.x; v < nv; v += 1024) {
        v4i t4 = ldnt4i(tgt + base + (v << 2));
        atomicAdd(&cnt[t4.x >> SHIFT], 1);
        atomicAdd(&cnt[t4.y >> SHIFT], 1);
        atomicAdd(&cnt[t4.z >> SHIFT], 1);
        atomicAdd(&cnt[t4.w >> SHIFT], 1);
    }
    for (int i = base + (nv << 2) + threadIdx.x; i < lim; i += 1024)
        atomicAdd(&cnt[tgt[i] >> SHIFT], 1);
    __syncthreads();
    for (int i = threadIdx.x; i < NB; i += 1024)
        Hg[i * nchunks + blockIdx.x] = cnt[i];
}

// in-place per-256-chunk exclusive scan; chunk totals to bsum
__global__ void scan_block_kernel(int* __restrict__ data, int* __restrict__ bsum,
                                  int n) {
    __shared__ int s[256];
    int i = blockIdx.x * 256 + threadIdx.x;
    int v = (i < n) ? data[i] : 0;
    s[threadIdx.x] = v;
    __syncthreads();
    #pragma unroll
    for (int d = 1; d < 256; d <<= 1) {
        int t = (threadIdx.x >= d) ? s[threadIdx.x - d] : 0;
        __syncthreads();
        s[threadIdx.x] += t;
        __syncthreads();
    }
    if (i < n) data[i] = s[threadIdx.x] - v;           // exclusive within chunk
    if (threadIdx.x == 255) bsum[blockIdx.x] = s[255]; // chunk total
}

__global__ void scan_bsum_kernel(int* __restrict__ bsum, int nblk) {
    __shared__ int s[1024];
    int tid = threadIdx.x;
    int v = (tid < nblk) ? bsum[tid] : 0;
    s[tid] = v;
    __syncthreads();
    for (int d = 1; d < 1024; d <<= 1) {
        int t = (tid >= d) ? s[tid - d] : 0;
        __syncthreads();
        s[tid] += t;
        __syncthreads();
    }
    if (tid < nblk) bsum[tid] = s[tid] - v;            // exclusive
}

// scatter records into (chunk,bucket)-exclusive regions via LDS cursors.
// All edge reads and rec writes are non-temporal (read/written once).
__global__ __launch_bounds__(1024) void p1_scatter_kernel(
        const int* __restrict__ src,
        const int* __restrict__ tgt,
        const float* __restrict__ e,
        const int* __restrict__ Hg,
        const int* __restrict__ bsum,
        int2* __restrict__ rec,
        int n_edges, int NB, int nchunks) {
    __shared__ int cur[MAXNB];
    for (int i = threadIdx.x; i < NB; i += 1024) {
        int j = i * nchunks + blockIdx.x;
        cur[i] = Hg[j] + bsum[j >> 8];
    }
    __syncthreads();
    int base = blockIdx.x * CHUNK;
    int lim  = min(base + CHUNK, n_edges);
    int n    = lim - base;
    int nv   = n >> 2;
    for (int v = threadIdx.x; v < nv; v += 1024) {
        int o = base + (v << 2);
        v4i s4 = ldnt4i(src + o);
        v4i t4 = ldnt4i(tgt + o);
        v4f e4 = ldnt4f(e + o);
        int p0 = atomicAdd(&cur[t4.x >> SHIFT], 1);
        int p1 = atomicAdd(&cur[t4.y >> SHIFT], 1);
        int p2 = atomicAdd(&cur[t4.z >> SHIFT], 1);
        int p3 = atomicAdd(&cur[t4.w >> SHIFT], 1);
        stnt2i(&rec[p0], s4.x | ((t4.x & (BNODES - 1)) << 17), __float_as_int(e4.x));
        stnt2i(&rec[p1], s4.y | ((t4.y & (BNODES - 1)) << 17), __float_as_int(e4.y));
        stnt2i(&rec[p2], s4.z | ((t4.z & (BNODES - 1)) << 17), __float_as_int(e4.z));
        stnt2i(&rec[p3], s4.w | ((t4.w & (BNODES - 1)) << 17), __float_as_int(e4.w));
    }
    for (int i = base + (nv << 2) + threadIdx.x; i < lim; i += 1024) {
        int t = tgt[i];
        int pos = atomicAdd(&cur[t >> SHIFT], 1);
        stnt2i(&rec[pos], src[i] | ((t & (BNODES - 1)) << 17), __float_as_int(e[i]));
    }
}

// one 512-thread block per 128-node bucket, bf16 x table:
//  pass 1: records -> regs (NT) + per-node rank (ONE LDS atomic per record)
//  scan:   128-entry exclusive scan; pass 2: direct node-sorted store
//  gather: 32 groups x 16 lanes (lane = 2 feats); 8-deep MLP; NT out write.
__global__ __launch_bounds__(ATHR) void p2_apply_bf16_kernel(
        const unsigned int* __restrict__ xhu,
        const int2* __restrict__ rec,
        const int* __restrict__ Hg, const int* __restrict__ bsum,
        float* __restrict__ out,
        int n_edges, int n_nodes, int NB, int nchunks) {
    __shared__ int2 srt[CAP];                 // 24 KB node-sorted records
    __shared__ int  cnt[BNODES];
    __shared__ int  off[BNODES + 1];
    __shared__ int  stmp[BNODES];

    int tid  = threadIdx.x;
    int b    = blockIdx.x;
    int j0   = b * nchunks;
    int base = Hg[j0] + bsum[j0 >> 8];
    int end;
    if (b + 1 < NB) {
        int j1 = (b + 1) * nchunks;
        end = Hg[j1] + bsum[j1 >> 8];
    } else {
        end = n_edges;
    }
    int nrec = end - base;

    if (nrec <= CAP) {
        if (tid < BNODES) cnt[tid] = 0;
        __syncthreads();
        // ---- pass 1: read records (NT) to regs + rank ----
        int2 myrec[KMAX];
        int  myln[KMAX];
        int  myrk[KMAX];
        #pragma unroll
        for (int k = 0; k < KMAX; ++k) {
            int r = tid + k * ATHR;
            myln[k] = -1;
            if (r < nrec) {
                int2 a = ldnt2i(&rec[base + r]);
                myrec[k] = a;
                int ln = (a.x >> 17) & (BNODES - 1);
                myln[k] = ln;
                myrk[k] = atomicAdd(&cnt[ln], 1);
            }
        }
        __syncthreads();
        // ---- 128-entry exclusive scan ----
        int v = (tid < BNODES) ? cnt[tid] : 0;
        if (tid < BNODES) stmp[tid] = v;
        __syncthreads();
        #pragma unroll
        for (int d = 1; d < BNODES; d <<= 1) {
            int t = (tid < BNODES && tid >= d) ? stmp[tid - d] : 0;
            __syncthreads();
            if (tid < BNODES) stmp[tid] += t;
            __syncthreads();
        }
        if (tid < BNODES) off[tid] = stmp[tid] - v;
        if (tid == 0) off[BNODES] = nrec;
        __syncthreads();
        // ---- pass 2: direct node-sorted store ----
        #pragma unroll
        for (int k = 0; k < KMAX; ++k) {
            if (myln[k] >= 0)
                srt[off[myln[k]] + myrk[k]] = myrec[k];
        }
        __syncthreads();
        // ---- gather: 32 groups x 16 lanes; 8-deep MLP (xh stays cached) ----
        int f2 = tid & 15;
        int g  = tid >> 4;
        for (int ln = g; ln < BNODES; ln += 32) {
            int p  = off[ln];
            int pe = off[ln + 1];
            float ax = 0.0f, ay = 0.0f;
            for (; p + 7 < pe; p += 8) {
                int2 r0 = srt[p];
                int2 r1 = srt[p + 1];
                int2 r2 = srt[p + 2];
                int2 r3 = srt[p + 3];
                int2 r4 = srt[p + 4];
                int2 r5 = srt[p + 5];
                int2 r6 = srt[p + 6];
                int2 r7 = srt[p + 7];
                unsigned int h0 = xhu[((r0.x & 0x1FFFF) << 4) + f2];
                unsigned int h1 = xhu[((r1.x & 0x1FFFF) << 4) + f2];
                unsigned int h2 = xhu[((r2.x & 0x1FFFF) << 4) + f2];
                unsigned int h3 = xhu[((r3.x & 0x1FFFF) << 4) + f2];
                unsigned int h4 = xhu[((r4.x & 0x1FFFF) << 4) + f2];
                unsigned int h5 = xhu[((r5.x & 0x1FFFF) << 4) + f2];
                unsigned int h6 = xhu[((r6.x & 0x1FFFF) << 4) + f2];
                unsigned int h7 = xhu[((r7.x & 0x1FFFF) << 4) + f2];
                float e0 = __int_as_float(r0.y), e1 = __int_as_float(r1.y);
                float e2 = __int_as_float(r2.y), e3 = __int_as_float(r3.y);
                float e4 = __int_as_float(r4.y), e5 = __int_as_float(r5.y);
                float e6 = __int_as_float(r6.y), e7 = __int_as_float(r7.y);
                ax += __uint_as_float(h0 << 16) * e0 + __uint_as_float(h1 << 16) * e1
                    + __uint_as_float(h2 << 16) * e2 + __uint_as_float(h3 << 16) * e3
                    + __uint_as_float(h4 << 16) * e4 + __uint_as_float(h5 << 16) * e5
                    + __uint_as_float(h6 << 16) * e6 + __uint_as_float(h7 << 16) * e7;
                ay += __uint_as_float(h0 & 0xFFFF0000u) * e0 + __uint_as_float(h1 & 0xFFFF0000u) * e1
                    + __uint_as_float(h2 & 0xFFFF0000u) * e2 + __uint_as_float(h3 & 0xFFFF0000u) * e3
                    + __uint_as_float(h4 & 0xFFFF0000u) * e4 + __uint_as_float(h5 & 0xFFFF0000u) * e5
                    + __uint_as_float(h6 & 0xFFFF0000u) * e6 + __uint_as_float(h7 & 0xFFFF0000u) * e7;
            }
            for (; p < pe; ++p) {
                int2 r0 = srt[p];
                unsigned int h0 = xhu[((r0.x & 0x1FFFF) << 4) + f2];
                float e0 = __int_as_float(r0.y);
                ax += __uint_as_float(h0 << 16) * e0;
                ay += __uint_as_float(h0 & 0xFFFF0000u) * e0;
            }
            int node = (b << SHIFT) + ln;
            if (node < n_nodes)
                stnt2f(out + (long long)node * D_FEAT + 2 * f2, ax, ay);
        }
    } else {
        // ---- slow path: LDS fp32 accumulate (correctness only) ----
        float* accS = (float*)srt;     // 16 KB of the 24 KB buffer
        for (int i = tid; i < BNODES * D_FEAT; i += ATHR) accS[i] = 0.0f;
        __syncthreads();
        int f2 = tid & 15;
        for (int r = base + (tid >> 4); r < end; r += (ATHR >> 4)) {
            int2 a = rec[r];
            unsigned int h = xhu[((a.x & 0x1FFFF) << 4) + f2];
            float ev = __int_as_float(a.y);
            int ln = (a.x >> 17) & (BNODES - 1);
            atomicAdd(&accS[ln * D_FEAT + 2 * f2],     __uint_as_float(h << 16) * ev);
            atomicAdd(&accS[ln * D_FEAT + 2 * f2 + 1], __uint_as_float(h & 0xFFFF0000u) * ev);
        }
        __syncthreads();
        int out0 = b << SHIFT;
        for (int i = tid; i < BNODES * D_FEAT; i += ATHR) {
            int node = out0 + (i >> 5);
            if (node < n_nodes) out[(long long)out0 * D_FEAT + i] = accS[i];
        }
    }
}

// round-9/11 fp32 apply (tier when ws can't hold the bf16 table)
__global__ __launch_bounds__(ATHR) void p2_apply_f32_kernel(
        const float* __restrict__ x, const int2* __restrict__ rec,
        const int* __restrict__ Hg, const int* __restrict__ bsum,
        float* __restrict__ out,
        int n_edges, int n_nodes, int NB, int nchunks) {
    __shared__ int2 srt[CAP];
    __shared__ int  cnt[BNODES];
    __shared__ int  off[BNODES + 1];
    __shared__ int  stmp[BNODES];

    int tid  = threadIdx.x;
    int b    = blockIdx.x;
    int j0   = b * nchunks;
    int base = Hg[j0] + bsum[j0 >> 8];
    int end;
    if (b + 1 < NB) {
        int j1 = (b + 1) * nchunks;
        end = Hg[j1] + bsum[j1 >> 8];
    } else {
        end = n_edges;
    }
    int nrec = end - base;

    if (nrec <= CAP) {
        if (tid < BNODES) cnt[tid] = 0;
        __syncthreads();
        int2 myrec[KMAX];
        int  myln[KMAX];
        int  myrk[KMAX];
        #pragma unroll
        for (int k = 0; k < KMAX; ++k) {
            int r = tid + k * ATHR;
            myln[k] = -1;
            if (r < nrec) {
                int2 a = ldnt2i(&rec[base + r]);
                myrec[k] = a;
                int ln = (a.x >> 17) & (BNODES - 1);
                myln[k] = ln;
                myrk[k] = atomicAdd(&cnt[ln], 1);
            }
        }
        __syncthreads();
        int v = (tid < BNODES) ? cnt[tid] : 0;
        if (tid < BNODES) stmp[tid] = v;
        __syncthreads();
        #pragma unroll
        for (int d = 1; d < BNODES; d <<= 1) {
            int t = (tid < BNODES && tid >= d) ? stmp[tid - d] : 0;
            __syncthreads();
            if (tid < BNODES) stmp[tid] += t;
            __syncthreads();
        }
        if (tid < BNODES) off[tid] = stmp[tid] - v;
        if (tid == 0) off[BNODES] = nrec;
        __syncthreads();
        #pragma unroll
        for (int k = 0; k < KMAX; ++k) {
            if (myln[k] >= 0)
                srt[off[myln[k]] + myrk[k]] = myrec[k];
        }
        __syncthreads();
        int f = tid & 31;
        int g = tid >> 5;
        for (int ln = g; ln < BNODES; ln += 16) {
            int p  = off[ln];
            int pe = off[ln + 1];
            float acc = 0.0f;
            for (; p + 7 < pe; p += 8) {
                int2 r0 = srt[p];
                int2 r1 = srt[p + 1];
                int2 r2 = srt[p + 2];
                int2 r3 = srt[p + 3];
                int2 r4 = srt[p + 4];
                int2 r5 = srt[p + 5];
                int2 r6 = srt[p + 6];
                int2 r7 = srt[p + 7];
                float v0 = x[(r0.x & 0x1FFFF) * D_FEAT + f] * __int_as_float(r0.y);
                float v1 = x[(r1.x & 0x1FFFF) * D_FEAT + f] * __int_as_float(r1.y);
                float v2 = x[(r2.x & 0x1FFFF) * D_FEAT + f] * __int_as_float(r2.y);
                float v3 = x[(r3.x & 0x1FFFF) * D_FEAT + f] * __int_as_float(r3.y);
                float v4 = x[(r4.x & 0x1FFFF) * D_FEAT + f] * __int_as_float(r4.y);
                float v5 = x[(r5.x & 0x1FFFF) * D_FEAT + f] * __int_as_float(r5.y);
                float v6 = x[(r6.x & 0x1FFFF) * D_FEAT + f] * __int_as_float(r6.y);
                float v7 = x[(r7.x & 0x1FFFF) * D_FEAT + f] * __int_as_float(r7.y);
                acc += ((v0 + v1) + (v2 + v3)) + ((v4 + v5) + (v6 + v7));
            }
            for (; p < pe; ++p) {
                int2 r0 = srt[p];
                acc += x[(r0.x & 0x1FFFF) * D_FEAT + f] * __int_as_float(r0.y);
            }
            int node = (b << SHIFT) + ln;
            if (node < n_nodes)
                out[(long long)node * D_FEAT + f] = acc;
        }
    } else {
        float* accS = (float*)srt;
        for (int i = tid; i < BNODES * D_FEAT; i += ATHR) accS[i] = 0.0f;
        __syncthreads();
        int f = tid & 31;
        for (int r = base + (tid >> 5); r < end; r += (ATHR >> 5)) {
            int2 a = rec[r];
            float v = x[(a.x & 0x1FFFF) * D_FEAT + f] * __int_as_float(a.y);
            atomicAdd(&accS[((a.x >> 17) & (BNODES - 1)) * D_FEAT + f], v);
        }
        __syncthreads();
        int out0 = b << SHIFT;
        for (int i = tid; i < BNODES * D_FEAT; i += ATHR) {
            int node = out0 + (i >> 5);
            if (node < n_nodes) out[(long long)out0 * D_FEAT + i] = accS[i];
        }
    }
}

extern "C" void kernel_launch(void* const* d_in, const int* in_sizes, int n_in,
                              void* d_out, int out_size, void* d_ws, size_t ws_size,
                              hipStream_t stream) {
    const float* x = (const float*)d_in[0];
    const int*   a = (const int*)d_in[1];     // [2, n_edges] delivered as int32
    const float* e = (const float*)d_in[2];

    int n_x     = in_sizes[0];
    int n_edges = in_sizes[2];
    int n_nodes = out_size / D_FEAT;
    const int* src = a;
    const int* tgt = a + n_edges;
    float* out = (float*)d_out;

    int NB        = (n_nodes + BNODES - 1) >> SHIFT;
    int nchunks   = (n_edges + CHUNK - 1) / CHUNK;
    int scan_n    = NB * nchunks;
    int nblk_scan = (scan_n + 255) / 256;

    size_t xh_bytes   = ((size_t)n_x * 2 + 15) & ~(size_t)15;
    size_t rec_bytes  = (size_t)n_edges * sizeof(int2);
    size_t hg_bytes   = (size_t)scan_n * sizeof(int);
    size_t bsum_bytes = (size_t)nblk_scan * sizeof(int);
    size_t need_f32   = rec_bytes + hg_bytes + bsum_bytes;
    size_t need_bf16  = xh_bytes + need_f32;

    bool shape_ok = (NB <= MAXNB) && (nblk_scan <= 1024) && (n_nodes <= (1 << 17));

    if (!shape_ok || ws_size < need_f32) {
        // fallback: direct atomics (verified round 2, 171 us)
        int threads = 256;
        zero_out_kernel<<<(out_size + threads - 1) / threads, threads, 0, stream>>>(out, out_size);
        long long total = (long long)n_edges * D_FEAT;
        int blocks = (int)((total + threads - 1) / threads);
        scatter_add_kernel<<<blocks, threads, 0, stream>>>(x, src, tgt, e, out, n_edges);
        return;
    }

    bool use_bf16 = (ws_size >= need_bf16);

    char* p = (char*)d_ws;
    unsigned short* xh = nullptr;
    if (use_bf16) { xh = (unsigned short*)p; p += xh_bytes; }
    int2* rec  = (int2*)p; p += rec_bytes;
    int*  Hg   = (int*)p;  p += hg_bytes;
    int*  bsum = (int*)p;

    p1_hist_kernel<<<nchunks, 1024, 0, stream>>>(x, xh, n_x, tgt, Hg,
                                                 n_edges, NB, nchunks);
    scan_block_kernel<<<nblk_scan, 256, 0, stream>>>(Hg, bsum, scan_n);
    scan_bsum_kernel<<<1, 1024, 0, stream>>>(bsum, nblk_scan);
    p1_scatter_kernel<<<nchunks, 1024, 0, stream>>>(src, tgt, e, Hg, bsum, rec,
                                                    n_edges, NB, nchunks);
    if (use_bf16) {
        p2_apply_bf16_kernel<<<NB, ATHR, 0, stream>>>(
            (const unsigned int*)xh, rec, Hg, bsum, out,
            n_edges, n_nodes, NB, nchunks);
    } else {
        p2_apply_f32_kernel<<<NB, ATHR, 0, stream>>>(
            x, rec, Hg, bsum, out, n_edges, n_nodes, NB, nchunks);
    }
}

// Round 15
// 63.332 us; speedup vs baseline: 1.5108x; 1.5108x over previous
//
#include <hip/hip_runtime.h>
#include <hip/hip_bf16.h>

// out[tgt[i], :] += x[src[i], :] * e[i]   (fp32, D=32)
// Radix partition by 128-node target bucket; bf16 x table (row = one 64B
// line); per-bucket apply rank-sorts records, register-accumulated gather.
// Round 15: full NT revert (NT stores write through L2 on gfx950 -> 58->96us
// regression in r14). Single change vs r13: CHUNK 8192->16384, halving
// scatter's partial-line write amplification (avg run 10.5->21 records).

#define D_FEAT   32
#define SHIFT    7            // 128 nodes per bucket
#define BNODES   128
#define CHUNK    16384        // edges per partition block
#define MAXNB    1024
#define CAP      3072         // max records stageable in LDS per bucket
#define ATHR     512          // apply block threads
#define KMAX     (CAP / ATHR) // records per thread in staging (6)

__device__ __forceinline__ unsigned short f2bf(float v) {
    union { float f; unsigned int u; } c; c.f = v;
    unsigned int r = c.u + 0x7FFFu + ((c.u >> 16) & 1u);   // round-nearest-even
    return (unsigned short)(r >> 16);
}

// ---------------- fallback path (round-2, verified) ----------------
__global__ void zero_out_kernel(float* __restrict__ out, int n) {
    int i = blockIdx.x * blockDim.x + threadIdx.x;
    if (i < n) out[i] = 0.0f;
}

__global__ void scatter_add_kernel(const float* __restrict__ x,
                                   const int* __restrict__ src,
                                   const int* __restrict__ tgt,
                                   const float* __restrict__ e,
                                   float* __restrict__ out,
                                   int n_edges) {
    long long gid   = (long long)blockIdx.x * blockDim.x + threadIdx.x;
    long long total = (long long)n_edges * D_FEAT;
    if (gid >= total) return;
    int edge = (int)(gid >> 5);
    int f    = (int)(gid & 31);
    float m = x[(long long)src[edge] * D_FEAT + f] * e[edge];
    atomicAdd(&out[(long long)tgt[edge] * D_FEAT + f], m);
}

// ---------------- radix path ----------------

// conv (grid-stride prologue) + per-chunk histogram of target buckets.
// xh == nullptr skips the conv (f32 tier).
__global__ __launch_bounds__(1024) void p1_hist_kernel(
        const float* __restrict__ x, unsigned short* __restrict__ xh, int n_x,
        const int* __restrict__ tgt, int* __restrict__ Hg,
        int n_edges, int NB, int nchunks) {
    // ---- conv x -> bf16 (independent of hist; apply consumes xh later) ----
    if (xh) {
        int n4 = n_x >> 2;
        for (int i = blockIdx.x * 1024 + threadIdx.x; i < n4; i += nchunks * 1024) {
            float4 v = ((const float4*)x)[i];
            ushort4 h;
            h.x = f2bf(v.x); h.y = f2bf(v.y); h.z = f2bf(v.z); h.w = f2bf(v.w);
            ((ushort4*)xh)[i] = h;
        }
        if (blockIdx.x == 0) {
            for (int j = (n4 << 2) + threadIdx.x; j < n_x; j += 1024)
                xh[j] = f2bf(x[j]);
        }
    }
    // ---- histogram ----
    __shared__ int cnt[MAXNB];
    for (int i = threadIdx.x; i < NB; i += 1024) cnt[i] = 0;
    __syncthreads();
    int base = blockIdx.x * CHUNK;
    int lim  = min(base + CHUNK, n_edges);
    int n    = lim - base;
    int nv   = n >> 2;
    const int4* t4p = (const int4*)(tgt + base);
    for (int v = threadIdx.x; v < nv; v += 1024) {
        int4 t4 = t4p[v];
        atomicAdd(&cnt[t4.x >> SHIFT], 1);
        atomicAdd(&cnt[t4.y >> SHIFT], 1);
        atomicAdd(&cnt[t4.z >> SHIFT], 1);
        atomicAdd(&cnt[t4.w >> SHIFT], 1);
    }
    for (int i = base + (nv << 2) + threadIdx.x; i < lim; i += 1024)
        atomicAdd(&cnt[tgt[i] >> SHIFT], 1);
    __syncthreads();
    for (int i = threadIdx.x; i < NB; i += 1024)
        Hg[i * nchunks + blockIdx.x] = cnt[i];
}

// in-place per-256-chunk exclusive scan; chunk totals to bsum
__global__ void scan_block_kernel(int* __restrict__ data, int* __restrict__ bsum,
                                  int n) {
    __shared__ int s[256];
    int i = blockIdx.x * 256 + threadIdx.x;
    int v = (i < n) ? data[i] : 0;
    s[threadIdx.x] = v;
    __syncthreads();
    #pragma unroll
    for (int d = 1; d < 256; d <<= 1) {
        int t = (threadIdx.x >= d) ? s[threadIdx.x - d] : 0;
        __syncthreads();
        s[threadIdx.x] += t;
        __syncthreads();
    }
    if (i < n) data[i] = s[threadIdx.x] - v;           // exclusive within chunk
    if (threadIdx.x == 255) bsum[blockIdx.x] = s[255]; // chunk total
}

__global__ void scan_bsum_kernel(int* __restrict__ bsum, int nblk) {
    __shared__ int s[1024];
    int tid = threadIdx.x;
    int v = (tid < nblk) ? bsum[tid] : 0;
    s[tid] = v;
    __syncthreads();
    for (int d = 1; d < 1024; d <<= 1) {
        int t = (tid >= d) ? s[tid - d] : 0;
        __syncthreads();
        s[tid] += t;
        __syncthreads();
    }
    if (tid < nblk) bsum[tid] = s[tid] - v;            // exclusive
}

// scatter records into (chunk,bucket)-exclusive regions via LDS cursors.
// global offset of flat scan index j = Hg[j] + bsum[j>>8]  (add_base fused).
// rec = { src | (local_tgt << 17) , bits(e) }  (src < 2^17, local_tgt < 128)
__global__ __launch_bounds__(1024) void p1_scatter_kernel(
        const int* __restrict__ src,
        const int* __restrict__ tgt,
        const float* __restrict__ e,
        const int* __restrict__ Hg,
        const int* __restrict__ bsum,
        int2* __restrict__ rec,
        int n_edges, int NB, int nchunks) {
    __shared__ int cur[MAXNB];
    for (int i = threadIdx.x; i < NB; i += 1024) {
        int j = i * nchunks + blockIdx.x;
        cur[i] = Hg[j] + bsum[j >> 8];
    }
    __syncthreads();
    int base = blockIdx.x * CHUNK;
    int lim  = min(base + CHUNK, n_edges);
    int n    = lim - base;
    int nv   = n >> 2;
    const int4*   s4p = (const int4*)(src + base);
    const int4*   t4p = (const int4*)(tgt + base);
    const float4* e4p = (const float4*)(e + base);
    for (int v = threadIdx.x; v < nv; v += 1024) {
        int4   s4 = s4p[v];
        int4   t4 = t4p[v];
        float4 e4 = e4p[v];
        int p0 = atomicAdd(&cur[t4.x >> SHIFT], 1);
        int p1 = atomicAdd(&cur[t4.y >> SHIFT], 1);
        int p2 = atomicAdd(&cur[t4.z >> SHIFT], 1);
        int p3 = atomicAdd(&cur[t4.w >> SHIFT], 1);
        rec[p0] = make_int2(s4.x | ((t4.x & (BNODES - 1)) << 17), __float_as_int(e4.x));
        rec[p1] = make_int2(s4.y | ((t4.y & (BNODES - 1)) << 17), __float_as_int(e4.y));
        rec[p2] = make_int2(s4.z | ((t4.z & (BNODES - 1)) << 17), __float_as_int(e4.z));
        rec[p3] = make_int2(s4.w | ((t4.w & (BNODES - 1)) << 17), __float_as_int(e4.w));
    }
    for (int i = base + (nv << 2) + threadIdx.x; i < lim; i += 1024) {
        int t = tgt[i];
        int pos = atomicAdd(&cur[t >> SHIFT], 1);
        rec[pos] = make_int2(src[i] | ((t & (BNODES - 1)) << 17),
                             __float_as_int(e[i]));
    }
}

// one 512-thread block per 128-node bucket, bf16 x table:
//  pass 1: records -> regs + per-node rank (ONE LDS atomic per record)
//  scan:   128-entry exclusive scan (no atomics)
//  pass 2: direct node-sorted store into srt (no atomics, no sidx)
//  gather: 32 groups x 16 lanes (lane = 2 feats = whole row is ONE 64B line);
//          8-deep MLP; fp32 accumulate; coalesced out write (zeros isolated).
__global__ __launch_bounds__(ATHR) void p2_apply_bf16_kernel(
        const unsigned int* __restrict__ xhu,
        const int2* __restrict__ rec,
        const int* __restrict__ Hg, const int* __restrict__ bsum,
        float* __restrict__ out,
        int n_edges, int n_nodes, int NB, int nchunks) {
    __shared__ int2 srt[CAP];                 // 24 KB node-sorted records
    __shared__ int  cnt[BNODES];
    __shared__ int  off[BNODES + 1];
    __shared__ int  stmp[BNODES];

    int tid  = threadIdx.x;
    int b    = blockIdx.x;
    int j0   = b * nchunks;
    int base = Hg[j0] + bsum[j0 >> 8];
    int end;
    if (b + 1 < NB) {
        int j1 = (b + 1) * nchunks;
        end = Hg[j1] + bsum[j1 >> 8];
    } else {
        end = n_edges;
    }
    int nrec = end - base;

    if (nrec <= CAP) {
        if (tid < BNODES) cnt[tid] = 0;
        __syncthreads();
        // ---- pass 1: read records to regs + rank ----
        int2 myrec[KMAX];
        int  myln[KMAX];
        int  myrk[KMAX];
        #pragma unroll
        for (int k = 0; k < KMAX; ++k) {
            int r = tid + k * ATHR;
            myln[k] = -1;
            if (r < nrec) {
                int2 a = rec[base + r];
                myrec[k] = a;
                int ln = (a.x >> 17) & (BNODES - 1);
                myln[k] = ln;
                myrk[k] = atomicAdd(&cnt[ln], 1);
            }
        }
        __syncthreads();
        // ---- 128-entry exclusive scan ----
        int v = (tid < BNODES) ? cnt[tid] : 0;
        if (tid < BNODES) stmp[tid] = v;
        __syncthreads();
        #pragma unroll
        for (int d = 1; d < BNODES; d <<= 1) {
            int t = (tid < BNODES && tid >= d) ? stmp[tid - d] : 0;
            __syncthreads();
            if (tid < BNODES) stmp[tid] += t;
            __syncthreads();
        }
        if (tid < BNODES) off[tid] = stmp[tid] - v;
        if (tid == 0) off[BNODES] = nrec;
        __syncthreads();
        // ---- pass 2: direct node-sorted store ----
        #pragma unroll
        for (int k = 0; k < KMAX; ++k) {
            if (myln[k] >= 0)
                srt[off[myln[k]] + myrk[k]] = myrec[k];
        }
        __syncthreads();
        // ---- gather: 32 groups x 16 lanes; 8-deep MLP ----
        int f2 = tid & 15;
        int g  = tid >> 4;
        for (int ln = g; ln < BNODES; ln += 32) {
            int p  = off[ln];
            int pe = off[ln + 1];
            float ax = 0.0f, ay = 0.0f;
            for (; p + 7 < pe; p += 8) {
                int2 r0 = srt[p];
                int2 r1 = srt[p + 1];
                int2 r2 = srt[p + 2];
                int2 r3 = srt[p + 3];
                int2 r4 = srt[p + 4];
                int2 r5 = srt[p + 5];
                int2 r6 = srt[p + 6];
                int2 r7 = srt[p + 7];
                unsigned int h0 = xhu[((r0.x & 0x1FFFF) << 4) + f2];
                unsigned int h1 = xhu[((r1.x & 0x1FFFF) << 4) + f2];
                unsigned int h2 = xhu[((r2.x & 0x1FFFF) << 4) + f2];
                unsigned int h3 = xhu[((r3.x & 0x1FFFF) << 4) + f2];
                unsigned int h4 = xhu[((r4.x & 0x1FFFF) << 4) + f2];
                unsigned int h5 = xhu[((r5.x & 0x1FFFF) << 4) + f2];
                unsigned int h6 = xhu[((r6.x & 0x1FFFF) << 4) + f2];
                unsigned int h7 = xhu[((r7.x & 0x1FFFF) << 4) + f2];
                float e0 = __int_as_float(r0.y), e1 = __int_as_float(r1.y);
                float e2 = __int_as_float(r2.y), e3 = __int_as_float(r3.y);
                float e4 = __int_as_float(r4.y), e5 = __int_as_float(r5.y);
                float e6 = __int_as_float(r6.y), e7 = __int_as_float(r7.y);
                ax += __uint_as_float(h0 << 16) * e0 + __uint_as_float(h1 << 16) * e1
                    + __uint_as_float(h2 << 16) * e2 + __uint_as_float(h3 << 16) * e3
                    + __uint_as_float(h4 << 16) * e4 + __uint_as_float(h5 << 16) * e5
                    + __uint_as_float(h6 << 16) * e6 + __uint_as_float(h7 << 16) * e7;
                ay += __uint_as_float(h0 & 0xFFFF0000u) * e0 + __uint_as_float(h1 & 0xFFFF0000u) * e1
                    + __uint_as_float(h2 & 0xFFFF0000u) * e2 + __uint_as_float(h3 & 0xFFFF0000u) * e3
                    + __uint_as_float(h4 & 0xFFFF0000u) * e4 + __uint_as_float(h5 & 0xFFFF0000u) * e5
                    + __uint_as_float(h6 & 0xFFFF0000u) * e6 + __uint_as_float(h7 & 0xFFFF0000u) * e7;
            }
            for (; p < pe; ++p) {
                int2 r0 = srt[p];
                unsigned int h0 = xhu[((r0.x & 0x1FFFF) << 4) + f2];
                float e0 = __int_as_float(r0.y);
                ax += __uint_as_float(h0 << 16) * e0;
                ay += __uint_as_float(h0 & 0xFFFF0000u) * e0;
            }
            int node = (b << SHIFT) + ln;
            if (node < n_nodes) {
                float2 o; o.x = ax; o.y = ay;
                ((float2*)out)[node * (D_FEAT / 2) + f2] = o;
            }
        }
    } else {
        // ---- slow path: LDS fp32 accumulate (correctness only) ----
        float* accS = (float*)srt;     // 16 KB of the 24 KB buffer
        for (int i = tid; i < BNODES * D_FEAT; i += ATHR) accS[i] = 0.0f;
        __syncthreads();
        int f2 = tid & 15;
        for (int r = base + (tid >> 4); r < end; r += (ATHR >> 4)) {
            int2 a = rec[r];
            unsigned int h = xhu[((a.x & 0x1FFFF) << 4) + f2];
            float ev = __int_as_float(a.y);
            int ln = (a.x >> 17) & (BNODES - 1);
            atomicAdd(&accS[ln * D_FEAT + 2 * f2],     __uint_as_float(h << 16) * ev);
            atomicAdd(&accS[ln * D_FEAT + 2 * f2 + 1], __uint_as_float(h & 0xFFFF0000u) * ev);
        }
        __syncthreads();
        int out0 = b << SHIFT;
        for (int i = tid; i < BNODES * D_FEAT; i += ATHR) {
            int node = out0 + (i >> 5);
            if (node < n_nodes) out[(long long)out0 * D_FEAT + i] = accS[i];
        }
    }
}

// round-9/11 fp32 apply (tier when ws can't hold the bf16 table)
__global__ __launch_bounds__(ATHR) void p2_apply_f32_kernel(
        const float* __restrict__ x, const int2* __restrict__ rec,
        const int* __restrict__ Hg, const int* __restrict__ bsum,
        float* __restrict__ out,
        int n_edges, int n_nodes, int NB, int nchunks) {
    __shared__ int2 srt[CAP];
    __shared__ int  cnt[BNODES];
    __shared__ int  off[BNODES + 1];
    __shared__ int  stmp[BNODES];

    int tid  = threadIdx.x;
    int b    = blockIdx.x;
    int j0   = b * nchunks;
    int base = Hg[j0] + bsum[j0 >> 8];
    int end;
    if (b + 1 < NB) {
        int j1 = (b + 1) * nchunks;
        end = Hg[j1] + bsum[j1 >> 8];
    } else {
        end = n_edges;
    }
    int nrec = end - base;

    if (nrec <= CAP) {
        if (tid < BNODES) cnt[tid] = 0;
        __syncthreads();
        int2 myrec[KMAX];
        int  myln[KMAX];
        int  myrk[KMAX];
        #pragma unroll
        for (int k = 0; k < KMAX; ++k) {
            int r = tid + k * ATHR;
            myln[k] = -1;
            if (r < nrec) {
                int2 a = rec[base + r];
                myrec[k] = a;
                int ln = (a.x >> 17) & (BNODES - 1);
                myln[k] = ln;
                myrk[k] = atomicAdd(&cnt[ln], 1);
            }
        }
        __syncthreads();
        int v = (tid < BNODES) ? cnt[tid] : 0;
        if (tid < BNODES) stmp[tid] = v;
        __syncthreads();
        #pragma unroll
        for (int d = 1; d < BNODES; d <<= 1) {
            int t = (tid < BNODES && tid >= d) ? stmp[tid - d] : 0;
            __syncthreads();
            if (tid < BNODES) stmp[tid] += t;
            __syncthreads();
        }
        if (tid < BNODES) off[tid] = stmp[tid] - v;
        if (tid == 0) off[BNODES] = nrec;
        __syncthreads();
        #pragma unroll
        for (int k = 0; k < KMAX; ++k) {
            if (myln[k] >= 0)
                srt[off[myln[k]] + myrk[k]] = myrec[k];
        }
        __syncthreads();
        int f = tid & 31;
        int g = tid >> 5;
        for (int ln = g; ln < BNODES; ln += 16) {
            int p  = off[ln];
            int pe = off[ln + 1];
            float acc = 0.0f;
            for (; p + 7 < pe; p += 8) {
                int2 r0 = srt[p];
                int2 r1 = srt[p + 1];
                int2 r2 = srt[p + 2];
                int2 r3 = srt[p + 3];
                int2 r4 = srt[p + 4];
                int2 r5 = srt[p + 5];
                int2 r6 = srt[p + 6];
                int2 r7 = srt[p + 7];
                float v0 = x[(r0.x & 0x1FFFF) * D_FEAT + f] * __int_as_float(r0.y);
                float v1 = x[(r1.x & 0x1FFFF) * D_FEAT + f] * __int_as_float(r1.y);
                float v2 = x[(r2.x & 0x1FFFF) * D_FEAT + f] * __int_as_float(r2.y);
                float v3 = x[(r3.x & 0x1FFFF) * D_FEAT + f] * __int_as_float(r3.y);
                float v4 = x[(r4.x & 0x1FFFF) * D_FEAT + f] * __int_as_float(r4.y);
                float v5 = x[(r5.x & 0x1FFFF) * D_FEAT + f] * __int_as_float(r5.y);
                float v6 = x[(r6.x & 0x1FFFF) * D_FEAT + f] * __int_as_float(r6.y);
                float v7 = x[(r7.x & 0x1FFFF) * D_FEAT + f] * __int_as_float(r7.y);
                acc += ((v0 + v1) + (v2 + v3)) + ((v4 + v5) + (v6 + v7));
            }
            for (; p < pe; ++p) {
                int2 r0 = srt[p];
                acc += x[(r0.x & 0x1FFFF) * D_FEAT + f] * __int_as_float(r0.y);
            }
            int node = (b << SHIFT) + ln;
            if (node < n_nodes)
                out[(long long)node * D_FEAT + f] = acc;
        }
    } else {
        float* accS = (float*)srt;
        for (int i = tid; i < BNODES * D_FEAT; i += ATHR) accS[i] = 0.0f;
        __syncthreads();
        int f = tid & 31;
        for (int r = base + (tid >> 5); r < end; r += (ATHR >> 5)) {
            int2 a = rec[r];
            float v = x[(a.x & 0x1FFFF) * D_FEAT + f] * __int_as_float(a.y);
            atomicAdd(&accS[((a.x >> 17) & (BNODES - 1)) * D_FEAT + f], v);
        }
        __syncthreads();
        int out0 = b << SHIFT;
        for (int i = tid; i < BNODES * D_FEAT; i += ATHR) {
            int node = out0 + (i >> 5);
            if (node < n_nodes) out[(long long)out0 * D_FEAT + i] = accS[i];
        }
    }
}

extern "C" void kernel_launch(void* const* d_in, const int* in_sizes, int n_in,
                              void* d_out, int out_size, void* d_ws, size_t ws_size,
                              hipStream_t stream) {
    const float* x = (const float*)d_in[0];
    const int*   a = (const int*)d_in[1];     // [2, n_edges] delivered as int32
    const float* e = (const float*)d_in[2];

    int n_x     = in_sizes[0];
    int n_edges = in_sizes[2];
    int n_nodes = out_size / D_FEAT;
    const int* src = a;
    const int* tgt = a + n_edges;
    float* out = (float*)d_out;

    int NB        = (n_nodes + BNODES - 1) >> SHIFT;
    int nchunks   = (n_edges + CHUNK - 1) / CHUNK;
    int scan_n    = NB * nchunks;
    int nblk_scan = (scan_n + 255) / 256;

    size_t xh_bytes   = ((size_t)n_x * 2 + 15) & ~(size_t)15;
    size_t rec_bytes  = (size_t)n_edges * sizeof(int2);
    size_t hg_bytes   = (size_t)scan_n * sizeof(int);
    size_t bsum_bytes = (size_t)nblk_scan * sizeof(int);
    size_t need_f32   = rec_bytes + hg_bytes + bsum_bytes;
    size_t need_bf16  = xh_bytes + need_f32;

    bool shape_ok = (NB <= MAXNB) && (nblk_scan <= 1024) && (n_nodes <= (1 << 17));

    if (!shape_ok || ws_size < need_f32) {
        // fallback: direct atomics (verified round 2, 171 us)
        int threads = 256;
        zero_out_kernel<<<(out_size + threads - 1) / threads, threads, 0, stream>>>(out, out_size);
        long long total = (long long)n_edges * D_FEAT;
        int blocks = (int)((total + threads - 1) / threads);
        scatter_add_kernel<<<blocks, threads, 0, stream>>>(x, src, tgt, e, out, n_edges);
        return;
    }

    bool use_bf16 = (ws_size >= need_bf16);

    char* p = (char*)d_ws;
    unsigned short* xh = nullptr;
    if (use_bf16) { xh = (unsigned short*)p; p += xh_bytes; }
    int2* rec  = (int2*)p; p += rec_bytes;
    int*  Hg   = (int*)p;  p += hg_bytes;
    int*  bsum = (int*)p;

    p1_hist_kernel<<<nchunks, 1024, 0, stream>>>(x, xh, n_x, tgt, Hg,
                                                 n_edges, NB, nchunks);
    scan_block_kernel<<<nblk_scan, 256, 0, stream>>>(Hg, bsum, scan_n);
    scan_bsum_kernel<<<1, 1024, 0, stream>>>(bsum, nblk_scan);
    p1_scatter_kernel<<<nchunks, 1024, 0, stream>>>(src, tgt, e, Hg, bsum, rec,
                                                    n_edges, NB, nchunks);
    if (use_bf16) {
        p2_apply_bf16_kernel<<<NB, ATHR, 0, stream>>>(
            (const unsigned int*)xh, rec, Hg, bsum, out,
            n_edges, n_nodes, NB, nchunks);
    } else {
        p2_apply_f32_kernel<<<NB, ATHR, 0, stream>>>(
            x, rec, Hg, bsum, out, n_edges, n_nodes, NB, nchunks);
    }
}

// Round 16
// 58.030 us; speedup vs baseline: 1.6488x; 1.0914x over previous
//
#include <hip/hip_runtime.h>
#include <hip/hip_bf16.h>

// out[tgt[i], :] += x[src[i], :] * e[i]   (fp32, D=32)
// Radix partition by 128-node target bucket; bf16 x table (row = one 64B
// line); per-bucket apply rank-sorts records, register-accumulated gather.
// Round 16: exact revert to the round-13 configuration (best verified:
// 58.3 us). CHUNK=8192 (196 partition blocks; r15's 16384 cost concurrency),
// no NT hints (r14: NT stores write through L2 -> 8x write amp), no coop
// fusion (r12: grid.sync ~25us each on 8 XCDs).
// Final decomposition:  apply ~29us = MSHR/miss-latency floor on 1.6M
// 64B-line gathers; partition ~24us streaming; ~5us launch gaps.

#define D_FEAT   32
#define SHIFT    7            // 128 nodes per bucket
#define BNODES   128
#define CHUNK    8192         // edges per partition block
#define MAXNB    1024
#define CAP      3072         // max records stageable in LDS per bucket
#define ATHR     512          // apply block threads
#define KMAX     (CAP / ATHR) // records per thread in staging (6)

__device__ __forceinline__ unsigned short f2bf(float v) {
    union { float f; unsigned int u; } c; c.f = v;
    unsigned int r = c.u + 0x7FFFu + ((c.u >> 16) & 1u);   // round-nearest-even
    return (unsigned short)(r >> 16);
}

// ---------------- fallback path (round-2, verified) ----------------
__global__ void zero_out_kernel(float* __restrict__ out, int n) {
    int i = blockIdx.x * blockDim.x + threadIdx.x;
    if (i < n) out[i] = 0.0f;
}

__global__ void scatter_add_kernel(const float* __restrict__ x,
                                   const int* __restrict__ src,
                                   const int* __restrict__ tgt,
                                   const float* __restrict__ e,
                                   float* __restrict__ out,
                                   int n_edges) {
    long long gid   = (long long)blockIdx.x * blockDim.x + threadIdx.x;
    long long total = (long long)n_edges * D_FEAT;
    if (gid >= total) return;
    int edge = (int)(gid >> 5);
    int f    = (int)(gid & 31);
    float m = x[(long long)src[edge] * D_FEAT + f] * e[edge];
    atomicAdd(&out[(long long)tgt[edge] * D_FEAT + f], m);
}

// ---------------- radix path ----------------

// conv (grid-stride prologue) + per-chunk histogram of target buckets.
// xh == nullptr skips the conv (f32 tier).
__global__ __launch_bounds__(1024) void p1_hist_kernel(
        const float* __restrict__ x, unsigned short* __restrict__ xh, int n_x,
        const int* __restrict__ tgt, int* __restrict__ Hg,
        int n_edges, int NB, int nchunks) {
    // ---- conv x -> bf16 (independent of hist; apply consumes xh later) ----
    if (xh) {
        int n4 = n_x >> 2;
        for (int i = blockIdx.x * 1024 + threadIdx.x; i < n4; i += nchunks * 1024) {
            float4 v = ((const float4*)x)[i];
            ushort4 h;
            h.x = f2bf(v.x); h.y = f2bf(v.y); h.z = f2bf(v.z); h.w = f2bf(v.w);
            ((ushort4*)xh)[i] = h;
        }
        if (blockIdx.x == 0) {
            for (int j = (n4 << 2) + threadIdx.x; j < n_x; j += 1024)
                xh[j] = f2bf(x[j]);
        }
    }
    // ---- histogram ----
    __shared__ int cnt[MAXNB];
    for (int i = threadIdx.x; i < NB; i += 1024) cnt[i] = 0;
    __syncthreads();
    int base = blockIdx.x * CHUNK;
    int lim  = min(base + CHUNK, n_edges);
    int n    = lim - base;
    int nv   = n >> 2;
    const int4* t4p = (const int4*)(tgt + base);
    for (int v = threadIdx.x; v < nv; v += 1024) {
        int4 t4 = t4p[v];
        atomicAdd(&cnt[t4.x >> SHIFT], 1);
        atomicAdd(&cnt[t4.y >> SHIFT], 1);
        atomicAdd(&cnt[t4.z >> SHIFT], 1);
        atomicAdd(&cnt[t4.w >> SHIFT], 1);
    }
    for (int i = base + (nv << 2) + threadIdx.x; i < lim; i += 1024)
        atomicAdd(&cnt[tgt[i] >> SHIFT], 1);
    __syncthreads();
    for (int i = threadIdx.x; i < NB; i += 1024)
        Hg[i * nchunks + blockIdx.x] = cnt[i];
}

// in-place per-256-chunk exclusive scan; chunk totals to bsum
__global__ void scan_block_kernel(int* __restrict__ data, int* __restrict__ bsum,
                                  int n) {
    __shared__ int s[256];
    int i = blockIdx.x * 256 + threadIdx.x;
    int v = (i < n) ? data[i] : 0;
    s[threadIdx.x] = v;
    __syncthreads();
    #pragma unroll
    for (int d = 1; d < 256; d <<= 1) {
        int t = (threadIdx.x >= d) ? s[threadIdx.x - d] : 0;
        __syncthreads();
        s[threadIdx.x] += t;
        __syncthreads();
    }
    if (i < n) data[i] = s[threadIdx.x] - v;           // exclusive within chunk
    if (threadIdx.x == 255) bsum[blockIdx.x] = s[255]; // chunk total
}

__global__ void scan_bsum_kernel(int* __restrict__ bsum, int nblk) {
    __shared__ int s[1024];
    int tid = threadIdx.x;
    int v = (tid < nblk) ? bsum[tid] : 0;
    s[tid] = v;
    __syncthreads();
    for (int d = 1; d < 1024; d <<= 1) {
        int t = (tid >= d) ? s[tid - d] : 0;
        __syncthreads();
        s[tid] += t;
        __syncthreads();
    }
    if (tid < nblk) bsum[tid] = s[tid] - v;            // exclusive
}

// scatter records into (chunk,bucket)-exclusive regions via LDS cursors.
// global offset of flat scan index j = Hg[j] + bsum[j>>8]  (add_base fused).
// rec = { src | (local_tgt << 17) , bits(e) }  (src < 2^17, local_tgt < 128)
__global__ __launch_bounds__(1024) void p1_scatter_kernel(
        const int* __restrict__ src,
        const int* __restrict__ tgt,
        const float* __restrict__ e,
        const int* __restrict__ Hg,
        const int* __restrict__ bsum,
        int2* __restrict__ rec,
        int n_edges, int NB, int nchunks) {
    __shared__ int cur[MAXNB];
    for (int i = threadIdx.x; i < NB; i += 1024) {
        int j = i * nchunks + blockIdx.x;
        cur[i] = Hg[j] + bsum[j >> 8];
    }
    __syncthreads();
    int base = blockIdx.x * CHUNK;
    int lim  = min(base + CHUNK, n_edges);
    int n    = lim - base;
    int nv   = n >> 2;
    const int4*   s4p = (const int4*)(src + base);
    const int4*   t4p = (const int4*)(tgt + base);
    const float4* e4p = (const float4*)(e + base);
    for (int v = threadIdx.x; v < nv; v += 1024) {
        int4   s4 = s4p[v];
        int4   t4 = t4p[v];
        float4 e4 = e4p[v];
        int p0 = atomicAdd(&cur[t4.x >> SHIFT], 1);
        int p1 = atomicAdd(&cur[t4.y >> SHIFT], 1);
        int p2 = atomicAdd(&cur[t4.z >> SHIFT], 1);
        int p3 = atomicAdd(&cur[t4.w >> SHIFT], 1);
        rec[p0] = make_int2(s4.x | ((t4.x & (BNODES - 1)) << 17), __float_as_int(e4.x));
        rec[p1] = make_int2(s4.y | ((t4.y & (BNODES - 1)) << 17), __float_as_int(e4.y));
        rec[p2] = make_int2(s4.z | ((t4.z & (BNODES - 1)) << 17), __float_as_int(e4.z));
        rec[p3] = make_int2(s4.w | ((t4.w & (BNODES - 1)) << 17), __float_as_int(e4.w));
    }
    for (int i = base + (nv << 2) + threadIdx.x; i < lim; i += 1024) {
        int t = tgt[i];
        int pos = atomicAdd(&cur[t >> SHIFT], 1);
        rec[pos] = make_int2(src[i] | ((t & (BNODES - 1)) << 17),
                             __float_as_int(e[i]));
    }
}

// one 512-thread block per 128-node bucket, bf16 x table:
//  pass 1: records -> regs + per-node rank (ONE LDS atomic per record)
//  scan:   128-entry exclusive scan (no atomics)
//  pass 2: direct node-sorted store into srt (no atomics, no sidx)
//  gather: 32 groups x 16 lanes (lane = 2 feats = whole row is ONE 64B line);
//          8-deep MLP; fp32 accumulate; coalesced out write (zeros isolated).
__global__ __launch_bounds__(ATHR) void p2_apply_bf16_kernel(
        const unsigned int* __restrict__ xhu,
        const int2* __restrict__ rec,
        const int* __restrict__ Hg, const int* __restrict__ bsum,
        float* __restrict__ out,
        int n_edges, int n_nodes, int NB, int nchunks) {
    __shared__ int2 srt[CAP];                 // 24 KB node-sorted records
    __shared__ int  cnt[BNODES];
    __shared__ int  off[BNODES + 1];
    __shared__ int  stmp[BNODES];

    int tid  = threadIdx.x;
    int b    = blockIdx.x;
    int j0   = b * nchunks;
    int base = Hg[j0] + bsum[j0 >> 8];
    int end;
    if (b + 1 < NB) {
        int j1 = (b + 1) * nchunks;
        end = Hg[j1] + bsum[j1 >> 8];
    } else {
        end = n_edges;
    }
    int nrec = end - base;

    if (nrec <= CAP) {
        if (tid < BNODES) cnt[tid] = 0;
        __syncthreads();
        // ---- pass 1: read records to regs + rank ----
        int2 myrec[KMAX];
        int  myln[KMAX];
        int  myrk[KMAX];
        #pragma unroll
        for (int k = 0; k < KMAX; ++k) {
            int r = tid + k * ATHR;
            myln[k] = -1;
            if (r < nrec) {
                int2 a = rec[base + r];
                myrec[k] = a;
                int ln = (a.x >> 17) & (BNODES - 1);
                myln[k] = ln;
                myrk[k] = atomicAdd(&cnt[ln], 1);
            }
        }
        __syncthreads();
        // ---- 128-entry exclusive scan ----
        int v = (tid < BNODES) ? cnt[tid] : 0;
        if (tid < BNODES) stmp[tid] = v;
        __syncthreads();
        #pragma unroll
        for (int d = 1; d < BNODES; d <<= 1) {
            int t = (tid < BNODES && tid >= d) ? stmp[tid - d] : 0;
            __syncthreads();
            if (tid < BNODES) stmp[tid] += t;
            __syncthreads();
        }
        if (tid < BNODES) off[tid] = stmp[tid] - v;
        if (tid == 0) off[BNODES] = nrec;
        __syncthreads();
        // ---- pass 2: direct node-sorted store ----
        #pragma unroll
        for (int k = 0; k < KMAX; ++k) {
            if (myln[k] >= 0)
                srt[off[myln[k]] + myrk[k]] = myrec[k];
        }
        __syncthreads();
        // ---- gather: 32 groups x 16 lanes; 8-deep MLP ----
        int f2 = tid & 15;
        int g  = tid >> 4;
        for (int ln = g; ln < BNODES; ln += 32) {
            int p  = off[ln];
            int pe = off[ln + 1];
            float ax = 0.0f, ay = 0.0f;
            for (; p + 7 < pe; p += 8) {
                int2 r0 = srt[p];
                int2 r1 = srt[p + 1];
                int2 r2 = srt[p + 2];
                int2 r3 = srt[p + 3];
                int2 r4 = srt[p + 4];
                int2 r5 = srt[p + 5];
                int2 r6 = srt[p + 6];
                int2 r7 = srt[p + 7];
                unsigned int h0 = xhu[((r0.x & 0x1FFFF) << 4) + f2];
                unsigned int h1 = xhu[((r1.x & 0x1FFFF) << 4) + f2];
                unsigned int h2 = xhu[((r2.x & 0x1FFFF) << 4) + f2];
                unsigned int h3 = xhu[((r3.x & 0x1FFFF) << 4) + f2];
                unsigned int h4 = xhu[((r4.x & 0x1FFFF) << 4) + f2];
                unsigned int h5 = xhu[((r5.x & 0x1FFFF) << 4) + f2];
                unsigned int h6 = xhu[((r6.x & 0x1FFFF) << 4) + f2];
                unsigned int h7 = xhu[((r7.x & 0x1FFFF) << 4) + f2];
                float e0 = __int_as_float(r0.y), e1 = __int_as_float(r1.y);
                float e2 = __int_as_float(r2.y), e3 = __int_as_float(r3.y);
                float e4 = __int_as_float(r4.y), e5 = __int_as_float(r5.y);
                float e6 = __int_as_float(r6.y), e7 = __int_as_float(r7.y);
                ax += __uint_as_float(h0 << 16) * e0 + __uint_as_float(h1 << 16) * e1
                    + __uint_as_float(h2 << 16) * e2 + __uint_as_float(h3 << 16) * e3
                    + __uint_as_float(h4 << 16) * e4 + __uint_as_float(h5 << 16) * e5
                    + __uint_as_float(h6 << 16) * e6 + __uint_as_float(h7 << 16) * e7;
                ay += __uint_as_float(h0 & 0xFFFF0000u) * e0 + __uint_as_float(h1 & 0xFFFF0000u) * e1
                    + __uint_as_float(h2 & 0xFFFF0000u) * e2 + __uint_as_float(h3 & 0xFFFF0000u) * e3
                    + __uint_as_float(h4 & 0xFFFF0000u) * e4 + __uint_as_float(h5 & 0xFFFF0000u) * e5
                    + __uint_as_float(h6 & 0xFFFF0000u) * e6 + __uint_as_float(h7 & 0xFFFF0000u) * e7;
            }
            for (; p < pe; ++p) {
                int2 r0 = srt[p];
                unsigned int h0 = xhu[((r0.x & 0x1FFFF) << 4) + f2];
                float e0 = __int_as_float(r0.y);
                ax += __uint_as_float(h0 << 16) * e0;
                ay += __uint_as_float(h0 & 0xFFFF0000u) * e0;
            }
            int node = (b << SHIFT) + ln;
            if (node < n_nodes) {
                float2 o; o.x = ax; o.y = ay;
                ((float2*)out)[node * (D_FEAT / 2) + f2] = o;
            }
        }
    } else {
        // ---- slow path: LDS fp32 accumulate (correctness only) ----
        float* accS = (float*)srt;     // 16 KB of the 24 KB buffer
        for (int i = tid; i < BNODES * D_FEAT; i += ATHR) accS[i] = 0.0f;
        __syncthreads();
        int f2 = tid & 15;
        for (int r = base + (tid >> 4); r < end; r += (ATHR >> 4)) {
            int2 a = rec[r];
            unsigned int h = xhu[((a.x & 0x1FFFF) << 4) + f2];
            float ev = __int_as_float(a.y);
            int ln = (a.x >> 17) & (BNODES - 1);
            atomicAdd(&accS[ln * D_FEAT + 2 * f2],     __uint_as_float(h << 16) * ev);
            atomicAdd(&accS[ln * D_FEAT + 2 * f2 + 1], __uint_as_float(h & 0xFFFF0000u) * ev);
        }
        __syncthreads();
        int out0 = b << SHIFT;
        for (int i = tid; i < BNODES * D_FEAT; i += ATHR) {
            int node = out0 + (i >> 5);
            if (node < n_nodes) out[(long long)out0 * D_FEAT + i] = accS[i];
        }
    }
}

// round-9/11 fp32 apply (tier when ws can't hold the bf16 table)
__global__ __launch_bounds__(ATHR) void p2_apply_f32_kernel(
        const float* __restrict__ x, const int2* __restrict__ rec,
        const int* __restrict__ Hg, const int* __restrict__ bsum,
        float* __restrict__ out,
        int n_edges, int n_nodes, int NB, int nchunks) {
    __shared__ int2 srt[CAP];
    __shared__ int  cnt[BNODES];
    __shared__ int  off[BNODES + 1];
    __shared__ int  stmp[BNODES];

    int tid  = threadIdx.x;
    int b    = blockIdx.x;
    int j0   = b * nchunks;
    int base = Hg[j0] + bsum[j0 >> 8];
    int end;
    if (b + 1 < NB) {
        int j1 = (b + 1) * nchunks;
        end = Hg[j1] + bsum[j1 >> 8];
    } else {
        end = n_edges;
    }
    int nrec = end - base;

    if (nrec <= CAP) {
        if (tid < BNODES) cnt[tid] = 0;
        __syncthreads();
        int2 myrec[KMAX];
        int  myln[KMAX];
        int  myrk[KMAX];
        #pragma unroll
        for (int k = 0; k < KMAX; ++k) {
            int r = tid + k * ATHR;
            myln[k] = -1;
            if (r < nrec) {
                int2 a = rec[base + r];
                myrec[k] = a;
                int ln = (a.x >> 17) & (BNODES - 1);
                myln[k] = ln;
                myrk[k] = atomicAdd(&cnt[ln], 1);
            }
        }
        __syncthreads();
        int v = (tid < BNODES) ? cnt[tid] : 0;
        if (tid < BNODES) stmp[tid] = v;
        __syncthreads();
        #pragma unroll
        for (int d = 1; d < BNODES; d <<= 1) {
            int t = (tid < BNODES && tid >= d) ? stmp[tid - d] : 0;
            __syncthreads();
            if (tid < BNODES) stmp[tid] += t;
            __syncthreads();
        }
        if (tid < BNODES) off[tid] = stmp[tid] - v;
        if (tid == 0) off[BNODES] = nrec;
        __syncthreads();
        #pragma unroll
        for (int k = 0; k < KMAX; ++k) {
            if (myln[k] >= 0)
                srt[off[myln[k]] + myrk[k]] = myrec[k];
        }
        __syncthreads();
        int f = tid & 31;
        int g = tid >> 5;
        for (int ln = g; ln < BNODES; ln += 16) {
            int p  = off[ln];
            int pe = off[ln + 1];
            float acc = 0.0f;
            for (; p + 7 < pe; p += 8) {
                int2 r0 = srt[p];
                int2 r1 = srt[p + 1];
                int2 r2 = srt[p + 2];
                int2 r3 = srt[p + 3];
                int2 r4 = srt[p + 4];
                int2 r5 = srt[p + 5];
                int2 r6 = srt[p + 6];
                int2 r7 = srt[p + 7];
                float v0 = x[(r0.x & 0x1FFFF) * D_FEAT + f] * __int_as_float(r0.y);
                float v1 = x[(r1.x & 0x1FFFF) * D_FEAT + f] * __int_as_float(r1.y);
                float v2 = x[(r2.x & 0x1FFFF) * D_FEAT + f] * __int_as_float(r2.y);
                float v3 = x[(r3.x & 0x1FFFF) * D_FEAT + f] * __int_as_float(r3.y);
                float v4 = x[(r4.x & 0x1FFFF) * D_FEAT + f] * __int_as_float(r4.y);
                float v5 = x[(r5.x & 0x1FFFF) * D_FEAT + f] * __int_as_float(r5.y);
                float v6 = x[(r6.x & 0x1FFFF) * D_FEAT + f] * __int_as_float(r6.y);
                float v7 = x[(r7.x & 0x1FFFF) * D_FEAT + f] * __int_as_float(r7.y);
                acc += ((v0 + v1) + (v2 + v3)) + ((v4 + v5) + (v6 + v7));
            }
            for (; p < pe; ++p) {
                int2 r0 = srt[p];
                acc += x[(r0.x & 0x1FFFF) * D_FEAT + f] * __int_as_float(r0.y);
            }
            int node = (b << SHIFT) + ln;
            if (node < n_nodes)
                out[(long long)node * D_FEAT + f] = acc;
        }
    } else {
        float* accS = (float*)srt;
        for (int i = tid; i < BNODES * D_FEAT; i += ATHR) accS[i] = 0.0f;
        __syncthreads();
        int f = tid & 31;
        for (int r = base + (tid >> 5); r < end; r += (ATHR >> 5)) {
            int2 a = rec[r];
            float v = x[(a.x & 0x1FFFF) * D_FEAT + f] * __int_as_float(a.y);
            atomicAdd(&accS[((a.x >> 17) & (BNODES - 1)) * D_FEAT + f], v);
        }
        __syncthreads();
        int out0 = b << SHIFT;
        for (int i = tid; i < BNODES * D_FEAT; i += ATHR) {
            int node = out0 + (i >> 5);
            if (node < n_nodes) out[(long long)out0 * D_FEAT + i] = accS[i];
        }
    }
}

extern "C" void kernel_launch(void* const* d_in, const int* in_sizes, int n_in,
                              void* d_out, int out_size, void* d_ws, size_t ws_size,
                              hipStream_t stream) {
    const float* x = (const float*)d_in[0];
    const int*   a = (const int*)d_in[1];     // [2, n_edges] delivered as int32
    const float* e = (const float*)d_in[2];

    int n_x     = in_sizes[0];
    int n_edges = in_sizes[2];
    int n_nodes = out_size / D_FEAT;
    const int* src = a;
    const int* tgt = a + n_edges;
    float* out = (float*)d_out;

    int NB        = (n_nodes + BNODES - 1) >> SHIFT;
    int nchunks   = (n_edges + CHUNK - 1) / CHUNK;
    int scan_n    = NB * nchunks;
    int nblk_scan = (scan_n + 255) / 256;

    size_t xh_bytes   = ((size_t)n_x * 2 + 15) & ~(size_t)15;
    size_t rec_bytes  = (size_t)n_edges * sizeof(int2);
    size_t hg_bytes   = (size_t)scan_n * sizeof(int);
    size_t bsum_bytes = (size_t)nblk_scan * sizeof(int);
    size_t need_f32   = rec_bytes + hg_bytes + bsum_bytes;
    size_t need_bf16  = xh_bytes + need_f32;

    bool shape_ok = (NB <= MAXNB) && (nblk_scan <= 1024) && (n_nodes <= (1 << 17));

    if (!shape_ok || ws_size < need_f32) {
        // fallback: direct atomics (verified round 2, 171 us)
        int threads = 256;
        zero_out_kernel<<<(out_size + threads - 1) / threads, threads, 0, stream>>>(out, out_size);
        long long total = (long long)n_edges * D_FEAT;
        int blocks = (int)((total + threads - 1) / threads);
        scatter_add_kernel<<<blocks, threads, 0, stream>>>(x, src, tgt, e, out, n_edges);
        return;
    }

    bool use_bf16 = (ws_size >= need_bf16);

    char* p = (char*)d_ws;
    unsigned short* xh = nullptr;
    if (use_bf16) { xh = (unsigned short*)p; p += xh_bytes; }
    int2* rec  = (int2*)p; p += rec_bytes;
    int*  Hg   = (int*)p;  p += hg_bytes;
    int*  bsum = (int*)p;

    p1_hist_kernel<<<nchunks, 1024, 0, stream>>>(x, xh, n_x, tgt, Hg,
                                                 n_edges, NB, nchunks);
    scan_block_kernel<<<nblk_scan, 256, 0, stream>>>(Hg, bsum, scan_n);
    scan_bsum_kernel<<<1, 1024, 0, stream>>>(bsum, nblk_scan);
    p1_scatter_kernel<<<nchunks, 1024, 0, stream>>>(src, tgt, e, Hg, bsum, rec,
                                                    n_edges, NB, nchunks);
    if (use_bf16) {
        p2_apply_bf16_kernel<<<NB, ATHR, 0, stream>>>(
            (const unsigned int*)xh, rec, Hg, bsum, out,
            n_edges, n_nodes, NB, nchunks);
    } else {
        p2_apply_f32_kernel<<<NB, ATHR, 0, stream>>>(
            x, rec, Hg, bsum, out, n_edges, n_nodes, NB, nchunks);
    }
}